// Round 12
// baseline (85.884 us; speedup 1.0000x reference)
//
#include <hip/hip_runtime.h>

#define NPOS (254*254)   // 64516
#define NPOSP 64520
#define KTOP 128
#define CAP 4096

typedef __attribute__((ext_vector_type(8))) short short8;
typedef __attribute__((ext_vector_type(4))) float f32x4;

// ---------------- workspace layout (float offsets) ----------------
#define OFF_X     0                    // fp32 channel-last X3: [65536][64]
#define OFF_X2F   4194304              // bf16 X2: [1024][260][16] shorts -> ends 6324224
// --- aliases inside X2 region (X2 dead after conv2m) ---
#define OFF_CAND  4194304              // 4096 ints
#define OFF_CKEY  4198400              // 4096 uints
#define OFF_CRESC 4202496              // 4096*32 -> 4333568
#define OFF_POS   4333568              // 128 ints
#define OFF_CMAP  4333696              // 128 ints
#define OFF_REG   4333824              // 128*576 -> 4407552
#define OFF_ACC   4407552              // 2048 -> 4409600
#define OFF_S     4409600              // 576 -> 4410176
// --- after X2 region ---
#define OFF_BF    6324224              // 9216 -> 6333440
#define OFF_W1T   6333440              // 12288 -> 6345728
#define OFF_W2C   6345728              // 18432 -> 6364160
#define OFF_MAXV  6364160              // 64520 -> 6428680
#define OFF_HIST  6428680              // 8192 -> 6436872
#define OFF_GCNT  6436872              // 4

__device__ __forceinline__ unsigned short to_bf16(float f) {
    unsigned int u = __float_as_uint(f);
    u += 0x7FFFu + ((u >> 16) & 1u);        // RNE
    return (unsigned short)(u >> 16);
}
__device__ __forceinline__ unsigned int flipkey(float f) {
    unsigned int u = __float_as_uint(f);
    return (u & 0x80000000u) ? ~u : (u | 0x80000000u);
}
__device__ __forceinline__ float inv_flipkey(unsigned int k) {
    unsigned int u = (k & 0x80000000u) ? (k & 0x7FFFFFFFu) : ~k;
    return __uint_as_float(u);
}

// ---------------- setup: weight rearranges, fragment packs, zeroing ----------------
__global__ __launch_bounds__(256) void kt_kernel(const float* __restrict__ fw,
                                                 const float* __restrict__ cw,
                                                 float* __restrict__ w1t,
                                                 short* __restrict__ BF,
                                                 float* __restrict__ w2c,
                                                 float* __restrict__ maxv,
                                                 unsigned int* __restrict__ hist,
                                                 unsigned int* __restrict__ gcnt) {
    int t = blockIdx.x * 256 + threadIdx.x;
    if (t < 64 * 192) {                 // feat_w (64,192) -> w1t[k][oc]
        int oc = t / 192, k = t % 192;
        w1t[k * 64 + oc] = fw[t];
    }
    if (t < 18432) {
        // B fragments for MFMA
        int j = t & 7, l = (t >> 3) & 63, half = (t >> 9) & 1, s = t >> 10;
        int k = s * 32 + ((l >> 4) & 3) * 8 + j;
        int oc = half * 16 + (l & 15);
        int ch = k & 63, tap = k >> 6;
        int di = tap / 3, dj = tap % 3;
        BF[t] = (short)to_bf16(cw[((oc * 64 + ch) * 3 + di) * 3 + dj]);
        // w2c[(ch*9+tap)*32 + oc] fp32 for rescore
        int o2 = t & 31, tapch = t >> 5;
        int tap2 = tapch % 9, ch2 = tapch / 9;
        w2c[t] = cw[((o2 * 64 + ch2) * 3 + tap2 / 3) * 3 + tap2 % 3];
    }
    if (t < 8192) hist[t] = 0u;
    if (t < 4) maxv[NPOS + t] = -1e30f;
    if (t == 0) gcnt[0] = 0u;
}

// ---------------- conv1: stride8/ks8, 256 thr; fp32 channel-last X3 + bf16 X2 ----------------
__global__ __launch_bounds__(256) void conv1_kernel(const float* __restrict__ x1,
                                                    const float* __restrict__ w1t,
                                                    const float* __restrict__ fb,
                                                    float* __restrict__ X3,
                                                    short* __restrict__ X2) {
    const int lane = threadIdx.x & 63;
    const int g = __builtin_amdgcn_readfirstlane(threadIdx.x >> 6);
    const int r = blockIdx.y;
    const int c = blockIdx.x * 64 + lane;

    float acc[16];
#pragma unroll
    for (int cc = 0; cc < 16; ++cc) acc[cc] = 0.f;

    const float* __restrict__ xb = x1 + (size_t)r * 8 * 2048 + (size_t)c * 8;
    for (int seg = 0; seg < 24; ++seg) {
        const int ic = seg >> 3, i = seg & 7;
        const float* __restrict__ xr = xb + (size_t)ic * 2048 * 2048 + i * 2048;
        float4 a = *reinterpret_cast<const float4*>(xr);
        float4 b = *reinterpret_cast<const float4*>(xr + 4);
        float xs[8] = {a.x, a.y, a.z, a.w, b.x, b.y, b.z, b.w};
        const float* __restrict__ wseg = w1t + seg * 8 * 64 + g * 16;
#pragma unroll
        for (int j = 0; j < 8; ++j) {
            const float* __restrict__ wr = wseg + j * 64;
            float xj = xs[j];
#pragma unroll
            for (int cc = 0; cc < 16; ++cc) acc[cc] += xj * wr[cc];
        }
    }
    const int gpos = r * 256 + c;
    float vo[16];
    unsigned short bh[16];
#pragma unroll
    for (int cc = 0; cc < 16; ++cc) {
        float v = acc[cc] + fb[g * 16 + cc];
        v = v > 0.f ? v : 0.f;
        vo[cc] = v;
        bh[cc] = to_bf16(v);
    }
    float* __restrict__ x3p = X3 + (size_t)gpos * 64 + g * 16;
#pragma unroll
    for (int cc = 0; cc < 4; ++cc)
        *reinterpret_cast<float4*>(x3p + cc * 4) = *reinterpret_cast<float4*>(&vo[cc * 4]);
    short* xo = X2 + ((size_t)(r * 4 + g) * 260 + c) * 16;
    *reinterpret_cast<short8*>(xo)     = *reinterpret_cast<short8*>(&bh[0]);
    *reinterpret_cast<short8*>(xo + 8) = *reinterpret_cast<short8*>(&bh[8]);
}

// ---------------- conv2 via MFMA (bf16 approx): maxv only ----------------
__global__ __launch_bounds__(256) void conv2m_kernel(const short* __restrict__ X2,
                                                     const short* __restrict__ BF,
                                                     const float* __restrict__ cb,
                                                     float* __restrict__ maxv) {
    const int tid = threadIdx.x;
    const int lane = tid & 63;
    const int wv = tid >> 6;
    const int r = blockIdx.y;
    const int cbase = blockIdx.x * 64 + wv * 16;
    const int m16 = lane & 15;
    const int q = lane >> 4;
    const int c = cbase + m16;
    const int colterm = c * 16 + (q & 1) * 8;
    const int ghalf = q >> 1;

    const short* __restrict__ pb = BF + (size_t)lane * 8;

    f32x4 acc0 = {0.f, 0.f, 0.f, 0.f};
    f32x4 acc1 = {0.f, 0.f, 0.f, 0.f};
#pragma unroll
    for (int s = 0; s < 18; ++s) {
        const int tap = s >> 1;
        const int di = tap / 3, dj = tap % 3;
        const int row = (r + di) * 4 + (s & 1) * 2 + ghalf;
        const short* __restrict__ pa = X2 + (size_t)row * (260 * 16) + colterm + dj * 16;
        short8 av = *reinterpret_cast<const short8*>(pa);
        short8 b0 = *reinterpret_cast<const short8*>(pb + (size_t)(s * 2 + 0) * 512);
        short8 b1 = *reinterpret_cast<const short8*>(pb + (size_t)(s * 2 + 1) * 512);
        acc0 = __builtin_amdgcn_mfma_f32_16x16x32_bf16(av, b0, acc0, 0, 0, 0);
        acc1 = __builtin_amdgcn_mfma_f32_16x16x32_bf16(av, b1, acc1, 0, 0, 0);
    }

    const float bias0 = cb[m16];
    const float bias1 = cb[16 + m16];
    float mx[4];
#pragma unroll
    for (int g = 0; g < 4; ++g)
        mx[g] = fmaxf(acc0[g] + bias0, acc1[g] + bias1);
#pragma unroll
    for (int off = 1; off < 16; off <<= 1) {
#pragma unroll
        for (int g = 0; g < 4; ++g)
            mx[g] = fmaxf(mx[g], __shfl_xor(mx[g], off));
    }
    if (m16 == 0) {
#pragma unroll
        for (int g = 0; g < 4; ++g) {
            int cc = cbase + q * 4 + g;
            if (cc < 254) maxv[r * 254 + cc] = mx[g];
        }
    }
}

// ---------------- histogram of maxv (per-block LDS, low-contention merge) ----------------
__global__ __launch_bounds__(256) void hist_kernel(const float* __restrict__ maxv,
                                                   unsigned int* __restrict__ hist) {
    __shared__ unsigned int lh[8192];
    const int tid = threadIdx.x;
    for (int i = tid; i < 8192; i += 256) lh[i] = 0u;
    __syncthreads();
    const float4* __restrict__ mv4 = reinterpret_cast<const float4*>(maxv);
    const int n4 = NPOS / 4;   // 16129
    for (int i = blockIdx.x * 256 + tid; i < n4; i += gridDim.x * 256) {
        float4 v = mv4[i];
        atomicAdd(&lh[flipkey(v.x) >> 19], 1u);
        atomicAdd(&lh[flipkey(v.y) >> 19], 1u);
        atomicAdd(&lh[flipkey(v.z) >> 19], 1u);
        atomicAdd(&lh[flipkey(v.w) >> 19], 1u);
    }
    __syncthreads();
    for (int i = tid; i < 8192; i += 256) {
        unsigned int h = lh[i];
        if (h) atomicAdd(&hist[i], h);
    }
}

// ---------------- collect: boundary bin from hist (LDS), value-margin threshold, scan ----------------
__global__ __launch_bounds__(256) void collect_kernel(const unsigned int* __restrict__ hist,
                                                      const float* __restrict__ maxv,
                                                      int* __restrict__ candpos,
                                                      unsigned int* __restrict__ gcnt) {
    __shared__ unsigned int lh[8192];
    __shared__ unsigned int coarse[256];
    __shared__ unsigned int thrkeyS;
    const int tid = threadIdx.x;
    for (int k = 0; k < 32; ++k) lh[k * 256 + tid] = hist[k * 256 + tid];
    __syncthreads();
    unsigned int s = 0;
#pragma unroll
    for (int j = 0; j < 32; ++j) s += lh[tid * 32 + j];
    coarse[tid] = s;
    __syncthreads();
    if (tid == 0) {
        unsigned int cum = 0;
        int seg = 255;
        for (; seg > 0; --seg) {
            if (cum + coarse[seg] >= (unsigned)KTOP) break;
            cum += coarse[seg];
        }
        int b = seg * 32;
        for (int j = 31; j >= 0; --j) {
            unsigned int h = lh[seg * 32 + j];
            if (cum + h >= (unsigned)KTOP) { b = seg * 32 + j; break; }
            cum += h;
        }
        float vfloor = inv_flipkey((unsigned int)b << 19);
        thrkeyS = flipkey(vfloor - 0.08f);   // bf16-error margin in value space
    }
    __syncthreads();
    const unsigned int thrkey = thrkeyS;
    const float4* __restrict__ mv4 = reinterpret_cast<const float4*>(maxv);
    const int n4 = NPOSP / 4;
    for (int i = blockIdx.x * 256 + tid; i < n4; i += gridDim.x * 256) {
        float4 v = mv4[i];
        float vs[4] = {v.x, v.y, v.z, v.w};
#pragma unroll
        for (int l = 0; l < 4; ++l) {
            int idx = i * 4 + l;
            if (flipkey(vs[l]) >= thrkey && idx < NPOS) {
                unsigned int slot = atomicAdd(gcnt, 1u);
                if (slot < (unsigned)CAP) candpos[slot] = idx;
            }
        }
    }
}

// ---------------- exact fp32 rescore of candidates (channel-last X3, coalesced) ----------------
__global__ __launch_bounds__(64) void rescore_kernel(const int* __restrict__ candpos,
                                                     const unsigned int* __restrict__ gcnt,
                                                     const float* __restrict__ X3,
                                                     const float* __restrict__ w2c,
                                                     const float* __restrict__ cb,
                                                     unsigned int* __restrict__ candkey,
                                                     float* __restrict__ cresc) {
    unsigned int cn = gcnt[0];
    const int cnt = (int)(cn < (unsigned)CAP ? cn : (unsigned)CAP);
    const int ch = threadIdx.x;
    for (int cand = blockIdx.x; cand < cnt; cand += gridDim.x) {
        const int p = candpos[cand];
        const int r = p / 254, c = p % 254;
        float xv[9];
#pragma unroll
        for (int di = 0; di < 3; ++di)
#pragma unroll
            for (int dj = 0; dj < 3; ++dj)
                xv[di * 3 + dj] = X3[(size_t)((r + di) * 256 + (c + dj)) * 64 + ch];
        float acc[32];
#pragma unroll
        for (int o = 0; o < 32; ++o) acc[o] = 0.f;
        const float* __restrict__ wr = w2c + ch * 288;
#pragma unroll
        for (int tap = 0; tap < 9; ++tap) {
            float x = xv[tap];
#pragma unroll
            for (int o = 0; o < 32; ++o) acc[o] += x * wr[tap * 32 + o];
        }
        float mx = -1e30f;
#pragma unroll
        for (int o = 0; o < 32; ++o) {
            float t = acc[o];
#pragma unroll
            for (int off = 1; off < 64; off <<= 1) t += __shfl_xor(t, off);
            float v = t + cb[o];
            if (ch == 0) cresc[(size_t)cand * 32 + o] = v;
            mx = fmaxf(mx, v);
        }
        if (ch == 0) candkey[cand] = flipkey(mx);
    }
}

// ---------------- exact top-128 rank selection (multi-block) ----------------
__global__ __launch_bounds__(256) void rank_kernel(const unsigned int* __restrict__ candkey,
                                                   const int* __restrict__ candpos,
                                                   const unsigned int* __restrict__ gcnt,
                                                   int* __restrict__ pos_out,
                                                   int* __restrict__ candmap) {
    __shared__ unsigned long long keys[CAP];
    unsigned int cn = gcnt[0];
    const int n = (int)(cn < (unsigned)CAP ? cn : (unsigned)CAP);
    const int tid = threadIdx.x;
    for (int i = tid; i < n; i += 256)
        keys[i] = ((unsigned long long)candkey[i] << 32) |
                  (unsigned int)(~(unsigned int)candpos[i]);
    __syncthreads();
    const int i = blockIdx.x * 256 + tid;   // 32*256 = 8192 >= CAP
    if (i < n) {
        unsigned long long ki = keys[i];
        int rank = 0;
        for (int j = 0; j < n; ++j) rank += (keys[j] > ki) ? 1 : 0;
        if (rank < KTOP) {
            pos_out[rank] = candpos[i];
            candmap[rank] = i;
        }
    }
}

// ---------------- fused: per-row l2norm of patches + cls_out (channel-last X3, coalesced) ----------------
__global__ __launch_bounds__(64) void gather_kernel(const float* __restrict__ X3,
                                                    const float* __restrict__ cresc,
                                                    const int* __restrict__ pos,
                                                    const int* __restrict__ candmap,
                                                    float* __restrict__ regn,
                                                    float* __restrict__ out) {
    const int k = blockIdx.x;
    const int ch = threadIdx.x;
    const int p = pos[k];
    if (ch < 32) out[2048 + ch * 128 + k] = cresc[(size_t)candmap[k] * 32 + ch];

    const int r0 = p / 254, c0 = p % 254;
    float v[9];
    float ss = 0.f;
#pragma unroll
    for (int fi = 0; fi < 3; ++fi)
#pragma unroll
        for (int fj = 0; fj < 3; ++fj) {
            float t = X3[(size_t)((r0 + fi) * 256 + (c0 + fj)) * 64 + ch];
            v[fi * 3 + fj] = t;
            ss += t * t;
        }
#pragma unroll
    for (int o = 1; o < 64; o <<= 1) ss += __shfl_xor(ss, o);
    float scale = 1.0f / fmaxf(sqrtf(ss), 1e-12f);
#pragma unroll
    for (int q2 = 0; q2 < 9; ++q2)
        regn[(size_t)k * 576 + ch * 9 + q2] = v[q2] * scale;
}

// ---------------- colsum: S = colsum(regn) + 128*shift  (18 blocks, k-split 8) ----------------
__global__ __launch_bounds__(256) void colsum_kernel(const float* __restrict__ regn,
                                                     const float* __restrict__ shift,
                                                     float* __restrict__ S) {
    __shared__ float part[8][32];
    const int tid = threadIdx.x;
    const int jl = tid & 31;
    const int kg = tid >> 5;
    const int j = blockIdx.x * 32 + jl;
    float s = 0.f;
#pragma unroll
    for (int kk = 0; kk < 16; ++kk)
        s += regn[(size_t)(kg * 16 + kk) * 576 + j];
    part[kg][jl] = s;
    __syncthreads();
    if (kg == 0) {
        float t = part[0][jl];
#pragma unroll
        for (int g = 1; g < 8; ++g) t += part[g][jl];
        S[j] = t + 128.0f * shift[j];
    }
}

// ---------------- matvec: one wave per f (512 blocks x 4 waves) ----------------
__global__ __launch_bounds__(256) void matvec_kernel(const float* __restrict__ S,
                                                     const float* __restrict__ lw,
                                                     const float* __restrict__ lb,
                                                     float* __restrict__ accv) {
    const int lane = threadIdx.x & 63;
    const int wv = threadIdx.x >> 6;
    const int f = blockIdx.x * 4 + wv;
    const float* __restrict__ wr = lw + (size_t)f * 576;
    float s = 0.f;
#pragma unroll
    for (int jj = 0; jj < 9; ++jj)
        s += wr[jj * 64 + lane] * S[jj * 64 + lane];
#pragma unroll
    for (int off = 1; off < 64; off <<= 1) s += __shfl_xor(s, off);
    if (lane == 0) accv[f] = s + 128.0f * lb[f];
}

// ---------------- final l2norm -> desc ----------------
__global__ __launch_bounds__(1024) void finalize_kernel(const float* __restrict__ accv,
                                                        float* __restrict__ out) {
    __shared__ float red[32];
    int tid = threadIdx.x;
    float a = accv[tid], b = accv[tid + 1024];
    float ss = a * a + b * b;
#pragma unroll
    for (int o = 1; o < 64; o <<= 1) ss += __shfl_xor(ss, o);
    if ((tid & 63) == 0) red[tid >> 6] = ss;
    __syncthreads();
    if (tid < 16) {
        float t = red[tid];
#pragma unroll
        for (int o = 1; o < 16; o <<= 1) t += __shfl_xor(t, o);
        if (tid == 0) red[0] = t;
    }
    __syncthreads();
    float scale = 1.0f / fmaxf(sqrtf(red[0]), 1e-12f);
    out[tid] = a * scale;
    out[tid + 1024] = b * scale;
}

extern "C" void kernel_launch(void* const* d_in, const int* in_sizes, int n_in,
                              void* d_out, int out_size, void* d_ws, size_t ws_size,
                              hipStream_t stream) {
    const float* x1    = (const float*)d_in[0];
    const float* fw    = (const float*)d_in[1];
    const float* fb    = (const float*)d_in[2];
    const float* cw    = (const float*)d_in[3];
    const float* cb    = (const float*)d_in[4];
    const float* shift = (const float*)d_in[5];
    const float* lw    = (const float*)d_in[6];
    const float* lb    = (const float*)d_in[7];
    float* out = (float*)d_out;
    float* ws  = (float*)d_ws;

    float*        X3    = ws + OFF_X;
    short*        X2    = (short*)(ws + OFF_X2F);
    int*          CAND  = (int*)(ws + OFF_CAND);
    unsigned int* CKEY  = (unsigned int*)(ws + OFF_CKEY);
    float*        CRESC = ws + OFF_CRESC;
    int*          POS   = (int*)(ws + OFF_POS);
    int*          CMAP  = (int*)(ws + OFF_CMAP);
    float*        REGN  = ws + OFF_REG;
    float*        ACC   = ws + OFF_ACC;
    float*        S     = ws + OFF_S;
    short*        BF    = (short*)(ws + OFF_BF);
    float*        W1T   = ws + OFF_W1T;
    float*        W2C   = ws + OFF_W2C;
    float*        MAXV  = ws + OFF_MAXV;
    unsigned int* HIST  = (unsigned int*)(ws + OFF_HIST);
    unsigned int* GCNT  = (unsigned int*)(ws + OFF_GCNT);

    kt_kernel<<<72, 256, 0, stream>>>(fw, cw, W1T, BF, W2C, MAXV, HIST, GCNT);
    conv1_kernel<<<dim3(4, 256), 256, 0, stream>>>(x1, W1T, fb, X3, X2);
    conv2m_kernel<<<dim3(4, 254), 256, 0, stream>>>(X2, BF, cb, MAXV);
    hist_kernel<<<64, 256, 0, stream>>>(MAXV, HIST);
    collect_kernel<<<64, 256, 0, stream>>>(HIST, MAXV, CAND, GCNT);
    rescore_kernel<<<1024, 64, 0, stream>>>(CAND, GCNT, X3, W2C, cb, CKEY, CRESC);
    rank_kernel<<<32, 256, 0, stream>>>(CKEY, CAND, GCNT, POS, CMAP);
    gather_kernel<<<128, 64, 0, stream>>>(X3, CRESC, POS, CMAP, REGN, out);
    colsum_kernel<<<18, 256, 0, stream>>>(REGN, shift, S);
    matvec_kernel<<<512, 256, 0, stream>>>(S, lw, lb, ACC);
    finalize_kernel<<<1, 1024, 0, stream>>>(ACC, out);
}

// Round 13
// 83.197 us; speedup vs baseline: 1.0323x; 1.0323x over previous
//
#include <hip/hip_runtime.h>

#define NPOS (254*254)   // 64516
#define NPOSP 64520
#define KTOP 128
#define CAP 4096

typedef __attribute__((ext_vector_type(8))) short short8;
typedef __attribute__((ext_vector_type(4))) float f32x4;

// ---------------- workspace layout (float offsets) ----------------
#define OFF_X     0                    // fp32 planar X: 64*65536
#define OFF_X2F   4194304              // bf16 X2: [1024][260][16] shorts -> ends 6324224
// --- aliases inside X2 region (X2 dead after conv2m) ---
#define OFF_CAND  4194304              // 4096 ints
#define OFF_CKEY  4198400              // 4096 uints
#define OFF_CRESC 4202496              // 4096*32 -> 4333568
#define OFF_POS   4333568              // 128 ints
#define OFF_CMAP  4333696              // 128 ints
#define OFF_REG   4333824              // 128*576 -> 4407552
#define OFF_ACC   4407552              // 2048 -> 4409600
#define OFF_S     4409600              // 576 -> 4410176
// --- after X2 region ---
#define OFF_BF    6324224              // 9216 -> 6333440
#define OFF_W1T   6333440              // 12288 -> 6345728
#define OFF_W2C   6345728              // 18432 -> 6364160
#define OFF_MAXV  6364160              // 64520 -> 6428680
#define OFF_HIST  6428680              // 8192 -> 6436872
#define OFF_GCNT  6436872              // 4

__device__ __forceinline__ unsigned short to_bf16(float f) {
    unsigned int u = __float_as_uint(f);
    u += 0x7FFFu + ((u >> 16) & 1u);        // RNE
    return (unsigned short)(u >> 16);
}
__device__ __forceinline__ unsigned int flipkey(float f) {
    unsigned int u = __float_as_uint(f);
    return (u & 0x80000000u) ? ~u : (u | 0x80000000u);
}
__device__ __forceinline__ float inv_flipkey(unsigned int k) {
    unsigned int u = (k & 0x80000000u) ? (k & 0x7FFFFFFFu) : ~k;
    return __uint_as_float(u);
}

// ---------------- setup: weight rearranges, fragment packs, zeroing ----------------
__global__ __launch_bounds__(256) void kt_kernel(const float* __restrict__ fw,
                                                 const float* __restrict__ cw,
                                                 float* __restrict__ w1t,
                                                 short* __restrict__ BF,
                                                 float* __restrict__ w2c,
                                                 float* __restrict__ maxv,
                                                 unsigned int* __restrict__ hist,
                                                 unsigned int* __restrict__ gcnt) {
    int t = blockIdx.x * 256 + threadIdx.x;
    if (t < 64 * 192) {                 // feat_w (64,192) -> w1t[k][oc]
        int oc = t / 192, k = t % 192;
        w1t[k * 64 + oc] = fw[t];
    }
    if (t < 18432) {
        // B fragments for MFMA
        int j = t & 7, l = (t >> 3) & 63, half = (t >> 9) & 1, s = t >> 10;
        int k = s * 32 + ((l >> 4) & 3) * 8 + j;
        int oc = half * 16 + (l & 15);
        int ch = k & 63, tap = k >> 6;
        int di = tap / 3, dj = tap % 3;
        BF[t] = (short)to_bf16(cw[((oc * 64 + ch) * 3 + di) * 3 + dj]);
        // w2c[(ch*9+tap)*32 + oc] fp32 for rescore
        int o2 = t & 31, tapch = t >> 5;
        int tap2 = tapch % 9, ch2 = tapch / 9;
        w2c[t] = cw[((o2 * 64 + ch2) * 3 + tap2 / 3) * 3 + tap2 % 3];
    }
    if (t < 8192) hist[t] = 0u;
    if (t < 4) maxv[NPOS + t] = -1e30f;
    if (t == 0) gcnt[0] = 0u;
}

// ---------------- conv1: stride8/ks8, 256 thr (4 ch-groups of 16), R8-proven ----------------
__global__ __launch_bounds__(256) void conv1_kernel(const float* __restrict__ x1,
                                                    const float* __restrict__ w1t,
                                                    const float* __restrict__ fb,
                                                    float* __restrict__ X,
                                                    short* __restrict__ X2) {
    const int lane = threadIdx.x & 63;
    const int g = __builtin_amdgcn_readfirstlane(threadIdx.x >> 6);
    const int r = blockIdx.y;
    const int c = blockIdx.x * 64 + lane;

    float acc[16];
#pragma unroll
    for (int cc = 0; cc < 16; ++cc) acc[cc] = 0.f;

    const float* __restrict__ xb = x1 + (size_t)r * 8 * 2048 + (size_t)c * 8;
    for (int seg = 0; seg < 24; ++seg) {
        const int ic = seg >> 3, i = seg & 7;
        const float* __restrict__ xr = xb + (size_t)ic * 2048 * 2048 + i * 2048;
        float4 a = *reinterpret_cast<const float4*>(xr);
        float4 b = *reinterpret_cast<const float4*>(xr + 4);
        float xs[8] = {a.x, a.y, a.z, a.w, b.x, b.y, b.z, b.w};
        const float* __restrict__ wseg = w1t + seg * 8 * 64 + g * 16;
#pragma unroll
        for (int j = 0; j < 8; ++j) {
            const float* __restrict__ wr = wseg + j * 64;
            float xj = xs[j];
#pragma unroll
            for (int cc = 0; cc < 16; ++cc) acc[cc] += xj * wr[cc];
        }
    }
    const int gpos = r * 256 + c;
    unsigned short bh[16];
#pragma unroll
    for (int cc = 0; cc < 16; ++cc) {
        float v = acc[cc] + fb[g * 16 + cc];
        v = v > 0.f ? v : 0.f;
        X[(size_t)(g * 16 + cc) * 65536 + gpos] = v;
        bh[cc] = to_bf16(v);
    }
    short* xo = X2 + ((size_t)(r * 4 + g) * 260 + c) * 16;
    *reinterpret_cast<short8*>(xo)     = *reinterpret_cast<short8*>(&bh[0]);
    *reinterpret_cast<short8*>(xo + 8) = *reinterpret_cast<short8*>(&bh[8]);
}

// ---------------- conv2 via MFMA (bf16 approx): maxv only ----------------
__global__ __launch_bounds__(256) void conv2m_kernel(const short* __restrict__ X2,
                                                     const short* __restrict__ BF,
                                                     const float* __restrict__ cb,
                                                     float* __restrict__ maxv) {
    const int tid = threadIdx.x;
    const int lane = tid & 63;
    const int wv = tid >> 6;
    const int r = blockIdx.y;
    const int cbase = blockIdx.x * 64 + wv * 16;
    const int m16 = lane & 15;
    const int q = lane >> 4;
    const int c = cbase + m16;
    const int colterm = c * 16 + (q & 1) * 8;
    const int ghalf = q >> 1;

    const short* __restrict__ pb = BF + (size_t)lane * 8;

    f32x4 acc0 = {0.f, 0.f, 0.f, 0.f};
    f32x4 acc1 = {0.f, 0.f, 0.f, 0.f};
#pragma unroll
    for (int s = 0; s < 18; ++s) {
        const int tap = s >> 1;
        const int di = tap / 3, dj = tap % 3;
        const int row = (r + di) * 4 + (s & 1) * 2 + ghalf;
        const short* __restrict__ pa = X2 + (size_t)row * (260 * 16) + colterm + dj * 16;
        short8 av = *reinterpret_cast<const short8*>(pa);
        short8 b0 = *reinterpret_cast<const short8*>(pb + (size_t)(s * 2 + 0) * 512);
        short8 b1 = *reinterpret_cast<const short8*>(pb + (size_t)(s * 2 + 1) * 512);
        acc0 = __builtin_amdgcn_mfma_f32_16x16x32_bf16(av, b0, acc0, 0, 0, 0);
        acc1 = __builtin_amdgcn_mfma_f32_16x16x32_bf16(av, b1, acc1, 0, 0, 0);
    }

    const float bias0 = cb[m16];
    const float bias1 = cb[16 + m16];
    float mx[4];
#pragma unroll
    for (int g = 0; g < 4; ++g)
        mx[g] = fmaxf(acc0[g] + bias0, acc1[g] + bias1);
#pragma unroll
    for (int off = 1; off < 16; off <<= 1) {
#pragma unroll
        for (int g = 0; g < 4; ++g)
            mx[g] = fmaxf(mx[g], __shfl_xor(mx[g], off));
    }
    if (m16 == 0) {
#pragma unroll
        for (int g = 0; g < 4; ++g) {
            int cc = cbase + q * 4 + g;
            if (cc < 254) maxv[r * 254 + cc] = mx[g];
        }
    }
}

// ---------------- histogram of maxv (per-block LDS, low-contention merge) ----------------
__global__ __launch_bounds__(256) void hist_kernel(const float* __restrict__ maxv,
                                                   unsigned int* __restrict__ hist) {
    __shared__ unsigned int lh[8192];
    const int tid = threadIdx.x;
    for (int i = tid; i < 8192; i += 256) lh[i] = 0u;
    __syncthreads();
    const float4* __restrict__ mv4 = reinterpret_cast<const float4*>(maxv);
    const int n4 = NPOS / 4;   // 16129
    for (int i = blockIdx.x * 256 + tid; i < n4; i += gridDim.x * 256) {
        float4 v = mv4[i];
        atomicAdd(&lh[flipkey(v.x) >> 19], 1u);
        atomicAdd(&lh[flipkey(v.y) >> 19], 1u);
        atomicAdd(&lh[flipkey(v.z) >> 19], 1u);
        atomicAdd(&lh[flipkey(v.w) >> 19], 1u);
    }
    __syncthreads();
    for (int i = tid; i < 8192; i += 256) {
        unsigned int h = lh[i];
        if (h) atomicAdd(&hist[i], h);
    }
}

// ---------------- collect: boundary bin from hist (LDS), value-margin threshold, scan ----------------
__global__ __launch_bounds__(256) void collect_kernel(const unsigned int* __restrict__ hist,
                                                      const float* __restrict__ maxv,
                                                      int* __restrict__ candpos,
                                                      unsigned int* __restrict__ gcnt) {
    __shared__ unsigned int lh[8192];
    __shared__ unsigned int coarse[256];
    __shared__ unsigned int thrkeyS;
    const int tid = threadIdx.x;
    for (int k = 0; k < 32; ++k) lh[k * 256 + tid] = hist[k * 256 + tid];
    __syncthreads();
    unsigned int s = 0;
#pragma unroll
    for (int j = 0; j < 32; ++j) s += lh[tid * 32 + j];
    coarse[tid] = s;
    __syncthreads();
    if (tid == 0) {
        unsigned int cum = 0;
        int seg = 255;
        for (; seg > 0; --seg) {
            if (cum + coarse[seg] >= (unsigned)KTOP) break;
            cum += coarse[seg];
        }
        int b = seg * 32;
        for (int j = 31; j >= 0; --j) {
            unsigned int h = lh[seg * 32 + j];
            if (cum + h >= (unsigned)KTOP) { b = seg * 32 + j; break; }
            cum += h;
        }
        float vfloor = inv_flipkey((unsigned int)b << 19);
        thrkeyS = flipkey(vfloor - 0.08f);   // bf16-error margin in value space
    }
    __syncthreads();
    const unsigned int thrkey = thrkeyS;
    const float4* __restrict__ mv4 = reinterpret_cast<const float4*>(maxv);
    const int n4 = NPOSP / 4;
    for (int i = blockIdx.x * 256 + tid; i < n4; i += gridDim.x * 256) {
        float4 v = mv4[i];
        float vs[4] = {v.x, v.y, v.z, v.w};
#pragma unroll
        for (int l = 0; l < 4; ++l) {
            int idx = i * 4 + l;
            if (flipkey(vs[l]) >= thrkey && idx < NPOS) {
                unsigned int slot = atomicAdd(gcnt, 1u);
                if (slot < (unsigned)CAP) candpos[slot] = idx;
            }
        }
    }
}

// ---------------- exact fp32 rescore of candidates ----------------
__global__ __launch_bounds__(64) void rescore_kernel(const int* __restrict__ candpos,
                                                     const unsigned int* __restrict__ gcnt,
                                                     const float* __restrict__ X,
                                                     const float* __restrict__ w2c,
                                                     const float* __restrict__ cb,
                                                     unsigned int* __restrict__ candkey,
                                                     float* __restrict__ cresc) {
    unsigned int cn = gcnt[0];
    const int cnt = (int)(cn < (unsigned)CAP ? cn : (unsigned)CAP);
    const int ch = threadIdx.x;
    for (int cand = blockIdx.x; cand < cnt; cand += gridDim.x) {
        const int p = candpos[cand];
        const int r = p / 254, c = p % 254;
        float xv[9];
#pragma unroll
        for (int di = 0; di < 3; ++di)
#pragma unroll
            for (int dj = 0; dj < 3; ++dj)
                xv[di * 3 + dj] = X[(size_t)ch * 65536 + (r + di) * 256 + (c + dj)];
        float acc[32];
#pragma unroll
        for (int o = 0; o < 32; ++o) acc[o] = 0.f;
        const float* __restrict__ wr = w2c + ch * 288;
#pragma unroll
        for (int tap = 0; tap < 9; ++tap) {
            float x = xv[tap];
#pragma unroll
            for (int o = 0; o < 32; ++o) acc[o] += x * wr[tap * 32 + o];
        }
        float mx = -1e30f;
#pragma unroll
        for (int o = 0; o < 32; ++o) {
            float t = acc[o];
#pragma unroll
            for (int off = 1; off < 64; off <<= 1) t += __shfl_xor(t, off);
            float v = t + cb[o];
            if (ch == 0) cresc[(size_t)cand * 32 + o] = v;
            mx = fmaxf(mx, v);
        }
        if (ch == 0) candkey[cand] = flipkey(mx);
    }
}

// ---------------- exact top-128 rank selection (multi-block) ----------------
__global__ __launch_bounds__(256) void rank_kernel(const unsigned int* __restrict__ candkey,
                                                   const int* __restrict__ candpos,
                                                   const unsigned int* __restrict__ gcnt,
                                                   int* __restrict__ pos_out,
                                                   int* __restrict__ candmap) {
    __shared__ unsigned long long keys[CAP];
    unsigned int cn = gcnt[0];
    const int n = (int)(cn < (unsigned)CAP ? cn : (unsigned)CAP);
    const int tid = threadIdx.x;
    for (int i = tid; i < n; i += 256)
        keys[i] = ((unsigned long long)candkey[i] << 32) |
                  (unsigned int)(~(unsigned int)candpos[i]);
    __syncthreads();
    const int i = blockIdx.x * 256 + tid;   // 32*256 = 8192 >= CAP
    if (i < n) {
        unsigned long long ki = keys[i];
        int rank = 0;
        for (int j = 0; j < n; ++j) rank += (keys[j] > ki) ? 1 : 0;
        if (rank < KTOP) {
            pos_out[rank] = candpos[i];
            candmap[rank] = i;
        }
    }
}

// ---------------- fused: per-row l2norm of patches + cls_out from rescored values ----------------
__global__ __launch_bounds__(64) void gather_kernel(const float* __restrict__ X,
                                                    const float* __restrict__ cresc,
                                                    const int* __restrict__ pos,
                                                    const int* __restrict__ candmap,
                                                    float* __restrict__ regn,
                                                    float* __restrict__ out) {
    const int k = blockIdx.x;
    const int ch = threadIdx.x;
    const int p = pos[k];
    if (ch < 32) out[2048 + ch * 128 + k] = cresc[(size_t)candmap[k] * 32 + ch];

    const int r0 = p / 254, c0 = p % 254;
    float v[9];
    float ss = 0.f;
#pragma unroll
    for (int fi = 0; fi < 3; ++fi)
#pragma unroll
        for (int fj = 0; fj < 3; ++fj) {
            float t = X[(size_t)ch * 65536 + (r0 + fi) * 256 + (c0 + fj)];
            v[fi * 3 + fj] = t;
            ss += t * t;
        }
#pragma unroll
    for (int o = 1; o < 64; o <<= 1) ss += __shfl_xor(ss, o);
    float scale = 1.0f / fmaxf(sqrtf(ss), 1e-12f);
#pragma unroll
    for (int q2 = 0; q2 < 9; ++q2)
        regn[(size_t)k * 576 + ch * 9 + q2] = v[q2] * scale;
}

// ---------------- colsum: S = colsum(regn) + 128*shift  (18 blocks, k-split 8) ----------------
__global__ __launch_bounds__(256) void colsum_kernel(const float* __restrict__ regn,
                                                     const float* __restrict__ shift,
                                                     float* __restrict__ S) {
    __shared__ float part[8][32];
    const int tid = threadIdx.x;
    const int jl = tid & 31;
    const int kg = tid >> 5;
    const int j = blockIdx.x * 32 + jl;
    float s = 0.f;
#pragma unroll
    for (int kk = 0; kk < 16; ++kk)
        s += regn[(size_t)(kg * 16 + kk) * 576 + j];
    part[kg][jl] = s;
    __syncthreads();
    if (kg == 0) {
        float t = part[0][jl];
#pragma unroll
        for (int g = 1; g < 8; ++g) t += part[g][jl];
        S[j] = t + 128.0f * shift[j];
    }
}

// ---------------- matvec: one wave per f (512 blocks x 4 waves) ----------------
__global__ __launch_bounds__(256) void matvec_kernel(const float* __restrict__ S,
                                                     const float* __restrict__ lw,
                                                     const float* __restrict__ lb,
                                                     float* __restrict__ accv) {
    const int lane = threadIdx.x & 63;
    const int wv = threadIdx.x >> 6;
    const int f = blockIdx.x * 4 + wv;
    const float* __restrict__ wr = lw + (size_t)f * 576;
    float s = 0.f;
#pragma unroll
    for (int jj = 0; jj < 9; ++jj)
        s += wr[jj * 64 + lane] * S[jj * 64 + lane];
#pragma unroll
    for (int off = 1; off < 64; off <<= 1) s += __shfl_xor(s, off);
    if (lane == 0) accv[f] = s + 128.0f * lb[f];
}

// ---------------- final l2norm -> desc ----------------
__global__ __launch_bounds__(1024) void finalize_kernel(const float* __restrict__ accv,
                                                        float* __restrict__ out) {
    __shared__ float red[32];
    int tid = threadIdx.x;
    float a = accv[tid], b = accv[tid + 1024];
    float ss = a * a + b * b;
#pragma unroll
    for (int o = 1; o < 64; o <<= 1) ss += __shfl_xor(ss, o);
    if ((tid & 63) == 0) red[tid >> 6] = ss;
    __syncthreads();
    if (tid < 16) {
        float t = red[tid];
#pragma unroll
        for (int o = 1; o < 16; o <<= 1) t += __shfl_xor(t, o);
        if (tid == 0) red[0] = t;
    }
    __syncthreads();
    float scale = 1.0f / fmaxf(sqrtf(red[0]), 1e-12f);
    out[tid] = a * scale;
    out[tid + 1024] = b * scale;
}

extern "C" void kernel_launch(void* const* d_in, const int* in_sizes, int n_in,
                              void* d_out, int out_size, void* d_ws, size_t ws_size,
                              hipStream_t stream) {
    const float* x1    = (const float*)d_in[0];
    const float* fw    = (const float*)d_in[1];
    const float* fb    = (const float*)d_in[2];
    const float* cw    = (const float*)d_in[3];
    const float* cb    = (const float*)d_in[4];
    const float* shift = (const float*)d_in[5];
    const float* lw    = (const float*)d_in[6];
    const float* lb    = (const float*)d_in[7];
    float* out = (float*)d_out;
    float* ws  = (float*)d_ws;

    float*        X     = ws + OFF_X;
    short*        X2    = (short*)(ws + OFF_X2F);
    int*          CAND  = (int*)(ws + OFF_CAND);
    unsigned int* CKEY  = (unsigned int*)(ws + OFF_CKEY);
    float*        CRESC = ws + OFF_CRESC;
    int*          POS   = (int*)(ws + OFF_POS);
    int*          CMAP  = (int*)(ws + OFF_CMAP);
    float*        REGN  = ws + OFF_REG;
    float*        ACC   = ws + OFF_ACC;
    float*        S     = ws + OFF_S;
    short*        BF    = (short*)(ws + OFF_BF);
    float*        W1T   = ws + OFF_W1T;
    float*        W2C   = ws + OFF_W2C;
    float*        MAXV  = ws + OFF_MAXV;
    unsigned int* HIST  = (unsigned int*)(ws + OFF_HIST);
    unsigned int* GCNT  = (unsigned int*)(ws + OFF_GCNT);

    kt_kernel<<<72, 256, 0, stream>>>(fw, cw, W1T, BF, W2C, MAXV, HIST, GCNT);
    conv1_kernel<<<dim3(4, 256), 256, 0, stream>>>(x1, W1T, fb, X, X2);
    conv2m_kernel<<<dim3(4, 254), 256, 0, stream>>>(X2, BF, cb, MAXV);
    hist_kernel<<<64, 256, 0, stream>>>(MAXV, HIST);
    collect_kernel<<<64, 256, 0, stream>>>(HIST, MAXV, CAND, GCNT);
    rescore_kernel<<<1024, 64, 0, stream>>>(CAND, GCNT, X, W2C, cb, CKEY, CRESC);
    rank_kernel<<<32, 256, 0, stream>>>(CKEY, CAND, GCNT, POS, CMAP);
    gather_kernel<<<128, 64, 0, stream>>>(X, CRESC, POS, CMAP, REGN, out);
    colsum_kernel<<<18, 256, 0, stream>>>(REGN, shift, S);
    matvec_kernel<<<512, 256, 0, stream>>>(S, lw, lb, ACC);
    finalize_kernel<<<1, 1024, 0, stream>>>(ACC, out);
}